// Round 10
// baseline (88.233 us; speedup 1.0000x reference)
//
#include <hip/hip_runtime.h>
#include <hip/hip_fp16.h>

typedef __attribute__((ext_vector_type(8))) _Float16 half8;
typedef __attribute__((ext_vector_type(4))) float f32x4;

union U2H2 { unsigned int u; __half2 h; };

static __device__ __forceinline__ unsigned int pack2h(float a, float b) {
    U2H2 c; c.h = __floats2half2_rn(a, b); return c.u;
}
static __device__ __forceinline__ __half2 u_as_h2(unsigned int u) {
    U2H2 c; c.u = u; return c.h;
}

// swizzle: slot' = slot ^ (row&3) ^ ((row>>2)&3) — conflict-free for the
// 4-lane-per-row writes and the 16-consecutive-row fragment reads
#define SWZ(row, slot) ((slot) ^ ((row) & 3) ^ (((row) >> 2) & 3))

// fence LDS + barrier WITHOUT draining vmcnt (prefetched loads stay in flight)
#define LDS_BARRIER()                                                \
    do {                                                             \
        asm volatile("s_waitcnt lgkmcnt(0)" ::: "memory");           \
        __builtin_amdgcn_s_barrier();                                \
        __builtin_amdgcn_sched_barrier(0);                           \
    } while (0)

// Prep: blocks [0,nT): transpose x -> xth [B][N][32] fp16 (per-b planes);
// blocks [nT,nT+25): repack W -> Wrh[k][o][c] fp16.
__global__ __launch_bounds__(256) void prep_all(const float* __restrict__ x,
                                                const float* __restrict__ W,
                                                unsigned short* __restrict__ xth,
                                                unsigned short* __restrict__ Wrh,
                                                int N, int nT) {
    int bid = blockIdx.x, tid = threadIdx.x;
    if (bid >= nT) {
        int k = bid - nT;  // 0..24
#pragma unroll
        for (int it = 0; it < 8; ++it) {
            int r = tid + 256 * it;          // 0..2047 = o*32+c
            int o = r >> 5, c = r & 31;
            __half h = __float2half(W[o * 800 + c * 25 + k]);
            Wrh[k * 2048 + r] = *reinterpret_cast<unsigned short*>(&h);
        }
        return;
    }
    __shared__ float t[2][32][65];
    int n0 = bid * 64;
#pragma unroll
    for (int i = 0; i < 16; ++i) {
        int e = tid + 256 * i;               // [2][32][64]
        int b = e >> 11, c = (e >> 6) & 31, nl = e & 63;
        int n = n0 + nl;
        t[b][c][nl] = (n < N) ? x[(size_t)(b * 32 + c) * N + n] : 0.f;
    }
    __syncthreads();
    int nl = tid >> 2, q = tid & 3, n = n0 + nl;
    if (n < N) {
#pragma unroll
        for (int b = 0; b < 2; ++b) {
            uint4 p;
            p.x = pack2h(t[b][q * 8 + 0][nl], t[b][q * 8 + 1][nl]);
            p.y = pack2h(t[b][q * 8 + 2][nl], t[b][q * 8 + 3][nl]);
            p.z = pack2h(t[b][q * 8 + 4][nl], t[b][q * 8 + 5][nl]);
            p.w = pack2h(t[b][q * 8 + 6][nl], t[b][q * 8 + 7][nl]);
            *reinterpret_cast<uint4*>(xth + (((size_t)b * N + n) * 32 + q * 8)) = p;
        }
    }
}

// Fused gather + einsum + MFMA + bias. 128-thread blocks (2 waves), 32-n tile,
// one batch half per block (XCD-partitioned planes). All loop inputs are
// register-prefetched from global: idx/w depth-6, gathers depth-3, B depth-1.
__global__ __launch_bounds__(128) void fused_main(
    const unsigned short* __restrict__ xth,  // [2][N][32] fp16
    const unsigned short* __restrict__ Wrh,  // [25][64][32] fp16
    const float* __restrict__ bias,          // [64]
    const int* __restrict__ nidx,            // [N][25][3]
    const float* __restrict__ nw,            // [N][25][3]
    float* __restrict__ out,                 // [2][64][N] fp32
    int N, int nt)
{
    __shared__ __align__(16) unsigned char sA[2][2048];   // 32 n-rows x 64B
    __shared__ __align__(16) unsigned char sB[2][4096];   // 64 o-rows x 64B

    const int bid = blockIdx.x;
    const int b0 = (bid & 7) >> 2;                 // XCDs 0-3 -> b=0, 4-7 -> b=1
    const int tile = (bid >> 3) * 4 + (bid & 3);
    if (tile >= nt) return;
    const int n0 = tile * 32;
    const int tid = threadIdx.x;

    const int row = tid >> 2;                      // n-row 0..31 this thread gathers
    const int q   = tid & 3;                       // 16B quad slice
    const int nclamp = (n0 + row < N) ? (n0 + row) : (N - 1);
    const int*   ib = nidx + (size_t)nclamp * 75;
    const float* wb = nw   + (size_t)nclamp * 75;
    const unsigned short* xb = xth + (size_t)b0 * N * 32 + q * 8;  // + j*32

    const int wr_off = row * 64 + (SWZ(row, q) << 4);              // sA write

    // sB: thread stages slots tid and tid+128 (slot s: orow=s>>2, oq=s&3)
    const int s1 = tid + 128;
    const int sbo0 = (tid >> 2) * 64 + (SWZ((tid >> 2), (tid & 3)) << 4);
    const int sbo1 = (s1 >> 2) * 64 + (SWZ((s1 >> 2), (s1 & 3)) << 4);
    const int gbo0 = (tid >> 2) * 32 + (tid & 3) * 8;              // Wrh halfword offs
    const int gbo1 = (s1 >> 2) * 32 + (s1 & 3) * 8;

    const int l = tid & 63, wv = tid >> 6, c16 = l & 15, g = l >> 4;
    const int arow = 16 * wv + c16;                // rows 0..31
    const int rd_a = arow * 64 + (SWZ(arow, g) << 4);

    int3   ri[3];
    float3 rw[3];
    unsigned int rwh[3][3];
    uint4  rg[3][3];
    uint4  rB0, rB1;

    f32x4 acc[4];
#pragma unroll
    for (int ot = 0; ot < 4; ++ot) acc[ot] = (f32x4){0.f, 0.f, 0.f, 0.f};

    // ---- prologue: idx(0..2) -> gathers(0..2); idx(3..5); B(0) ----
#pragma unroll
    for (int kk = 0; kk < 3; ++kk) {
        ri[kk] = *reinterpret_cast<const int3*>(ib + kk * 3);
        rw[kk] = *reinterpret_cast<const float3*>(wb + kk * 3);
    }
#pragma unroll
    for (int kk = 0; kk < 3; ++kk) {
        rwh[kk][0] = pack2h(rw[kk].x, rw[kk].x);
        rwh[kk][1] = pack2h(rw[kk].y, rw[kk].y);
        rwh[kk][2] = pack2h(rw[kk].z, rw[kk].z);
        rg[kk][0] = *reinterpret_cast<const uint4*>(xb + ri[kk].x * 32);
        rg[kk][1] = *reinterpret_cast<const uint4*>(xb + ri[kk].y * 32);
        rg[kk][2] = *reinterpret_cast<const uint4*>(xb + ri[kk].z * 32);
        ri[kk] = *reinterpret_cast<const int3*>(ib + (kk + 3) * 3);
        rw[kk] = *reinterpret_cast<const float3*>(wb + (kk + 3) * 3);
    }
    rB0 = *reinterpret_cast<const uint4*>(Wrh + gbo0);
    rB1 = *reinterpret_cast<const uint4*>(Wrh + gbo1);

#pragma unroll
    for (int k = 0; k < 25; ++k) {
        const int gb = k % 3, buf = k & 1;

        // stage B slice; refill B(k+1)
        *reinterpret_cast<uint4*>(&sB[buf][sbo0]) = rB0;
        *reinterpret_cast<uint4*>(&sB[buf][sbo1]) = rB1;
        if (k + 1 < 25) {
            rB0 = *reinterpret_cast<const uint4*>(Wrh + (k + 1) * 2048 + gbo0);
            rB1 = *reinterpret_cast<const uint4*>(Wrh + (k + 1) * 2048 + gbo1);
        }

        // weighted fp16 sum of slice k's gathers -> sA
        {
            __half2 w0 = u_as_h2(rwh[gb][0]), w1 = u_as_h2(rwh[gb][1]), w2 = u_as_h2(rwh[gb][2]);
            uint4 v0 = rg[gb][0], v1 = rg[gb][1], v2 = rg[gb][2];
            uint4 p; U2H2 c;
            c.h = __hfma2(u_as_h2(v0.x), w0, __hfma2(u_as_h2(v1.x), w1, __hmul2(u_as_h2(v2.x), w2)));
            p.x = c.u;
            c.h = __hfma2(u_as_h2(v0.y), w0, __hfma2(u_as_h2(v1.y), w1, __hmul2(u_as_h2(v2.y), w2)));
            p.y = c.u;
            c.h = __hfma2(u_as_h2(v0.z), w0, __hfma2(u_as_h2(v1.z), w1, __hmul2(u_as_h2(v2.z), w2)));
            p.z = c.u;
            c.h = __hfma2(u_as_h2(v0.w), w0, __hfma2(u_as_h2(v1.w), w1, __hmul2(u_as_h2(v2.w), w2)));
            p.w = c.u;
            *reinterpret_cast<uint4*>(&sA[buf][wr_off]) = p;
        }

        // stage w(k+3) as half2, issue gathers(k+3), refill idx/w(k+6)
        if (k + 3 < 25) {
            rwh[gb][0] = pack2h(rw[gb].x, rw[gb].x);
            rwh[gb][1] = pack2h(rw[gb].y, rw[gb].y);
            rwh[gb][2] = pack2h(rw[gb].z, rw[gb].z);
            rg[gb][0] = *reinterpret_cast<const uint4*>(xb + ri[gb].x * 32);
            rg[gb][1] = *reinterpret_cast<const uint4*>(xb + ri[gb].y * 32);
            rg[gb][2] = *reinterpret_cast<const uint4*>(xb + ri[gb].z * 32);
            if (k + 6 < 25) {
                ri[gb] = *reinterpret_cast<const int3*>(ib + (k + 6) * 3);
                rw[gb] = *reinterpret_cast<const float3*>(wb + (k + 6) * 3);
            }
        }

        // one 2-wave barrier; vmem prefetch stays in flight
        LDS_BARRIER();

        // MFMA
        {
            half8 af = *reinterpret_cast<const half8*>(&sA[buf][rd_a]);
            __builtin_amdgcn_s_setprio(1);
#pragma unroll
            for (int ot = 0; ot < 4; ++ot) {
                int orow = ot * 16 + c16;
                half8 bf = *reinterpret_cast<const half8*>(
                    &sB[buf][orow * 64 + (SWZ(orow, g) << 4)]);
                acc[ot] = __builtin_amdgcn_mfma_f32_16x16x32_f16(af, bf, acc[ot], 0, 0, 0);
            }
            __builtin_amdgcn_s_setprio(0);
        }
    }

    // ---- epilogue: bias + store (D: o = ot*16+c16, n-row = 16wv+4g+i) ----
#pragma unroll
    for (int ot = 0; ot < 4; ++ot) {
        int o = ot * 16 + c16;
        float bv = bias[o];
#pragma unroll
        for (int i = 0; i < 4; ++i) {
            int n = n0 + 16 * wv + 4 * g + i;
            if (n < N) out[((size_t)b0 * 64 + o) * N + n] = acc[ot][i] + bv;
        }
    }
}

extern "C" void kernel_launch(void* const* d_in, const int* in_sizes, int n_in,
                              void* d_out, int out_size, void* d_ws, size_t ws_size,
                              hipStream_t stream) {
    const float* x    = (const float*)d_in[0];   // (2,32,N)
    const float* nw   = (const float*)d_in[1];   // (N,25,3)
    const float* W    = (const float*)d_in[2];   // (64,800)
    const float* bias = (const float*)d_in[3];   // (64,)
    const int*   nidx = (const int*)d_in[4];     // (N,25,3)
    float* out = (float*)d_out;

    int N = in_sizes[0] / 64;  // B*C = 64

    unsigned short* xth = (unsigned short*)d_ws;      // [2][N][32] fp16
    unsigned short* Wrh = xth + (size_t)2 * N * 32;   // [25][64][32] fp16

    int nT = (N + 63) / 64;
    prep_all<<<nT + 25, 256, 0, stream>>>(x, W, xth, Wrh, N, nT);

    int nt = (N + 31) / 32;                 // 32-n tiles per batch half
    int grid = ((nt + 3) / 4) * 8;          // 8-block groups: 4 tiles x 2 halves
    fused_main<<<grid, 128, 0, stream>>>(xth, Wrh, bias, nidx, nw, out, N, nt);
}

// Round 11
// 58.033 us; speedup vs baseline: 1.5204x; 1.5204x over previous
//
#include <hip/hip_runtime.h>
#include <hip/hip_fp16.h>

typedef __attribute__((ext_vector_type(8))) _Float16 half8;
typedef __attribute__((ext_vector_type(4))) float f32x4;

union U2H2 { unsigned int u; __half2 h; };

static __device__ __forceinline__ unsigned int pack2h(float a, float b) {
    U2H2 c; c.h = __floats2half2_rn(a, b); return c.u;
}
static __device__ __forceinline__ __half2 u_as_h2(unsigned int u) {
    U2H2 c; c.u = u; return c.h;
}
static __device__ __forceinline__ __half2 hi16(unsigned int u) {
    return u_as_h2(__builtin_amdgcn_perm(u, u, 0x03020302u));
}

// swizzle: slot' = slot ^ (row&3) ^ ((row>>2)&3) ^ ((row>>5)&1)
// verified <=2-way (free) for the 8-lane paired-line writes, the 4-lane B
// writes, and the 16-consecutive-row MFMA fragment reads
#define SWZ(row, slot) \
    ((slot) ^ ((row) & 3) ^ (((row) >> 2) & 3) ^ (((row) >> 5) & 1))

// fence LDS + barrier WITHOUT draining vmcnt (prefetched loads stay in flight)
#define LDS_BARRIER()                                                \
    do {                                                             \
        asm volatile("s_waitcnt lgkmcnt(0)" ::: "memory");           \
        __builtin_amdgcn_s_barrier();                                \
        __builtin_amdgcn_sched_barrier(0);                           \
    } while (0)

// Prep: blocks [0,nT): transpose x -> xth [N][2][32] fp16 (b-halves share a
// 128B line); blocks [nT,nT+25): repack W -> Wrh[k][o][c] fp16.
__global__ __launch_bounds__(256) void prep_all(const float* __restrict__ x,
                                                const float* __restrict__ W,
                                                unsigned short* __restrict__ xth,
                                                unsigned short* __restrict__ Wrh,
                                                int N, int nT) {
    int bid = blockIdx.x, tid = threadIdx.x;
    if (bid >= nT) {
        int k = bid - nT;  // 0..24
#pragma unroll
        for (int it = 0; it < 8; ++it) {
            int r = tid + 256 * it;          // 0..2047 = o*32+c
            int o = r >> 5, c = r & 31;
            __half h = __float2half(W[o * 800 + c * 25 + k]);
            Wrh[k * 2048 + r] = *reinterpret_cast<unsigned short*>(&h);
        }
        return;
    }
    __shared__ float t[2][32][65];
    int n0 = bid * 64;
#pragma unroll
    for (int i = 0; i < 16; ++i) {
        int e = tid + 256 * i;               // [2][32][64]
        int b = e >> 11, c = (e >> 6) & 31, nl = e & 63;
        int n = n0 + nl;
        t[b][c][nl] = (n < N) ? x[(size_t)(b * 32 + c) * N + n] : 0.f;
    }
    __syncthreads();
    int nl = tid >> 2, q = tid & 3, n = n0 + nl;
    if (n < N) {
#pragma unroll
        for (int b = 0; b < 2; ++b) {
            uint4 p;
            p.x = pack2h(t[b][q * 8 + 0][nl], t[b][q * 8 + 1][nl]);
            p.y = pack2h(t[b][q * 8 + 2][nl], t[b][q * 8 + 3][nl]);
            p.z = pack2h(t[b][q * 8 + 4][nl], t[b][q * 8 + 5][nl]);
            p.w = pack2h(t[b][q * 8 + 6][nl], t[b][q * 8 + 7][nl]);
            *reinterpret_cast<uint4*>(xth + ((size_t)n * 64 + b * 32 + q * 8)) = p;
        }
    }
}

// Fused gather + einsum + MFMA + bias. 32-n tile, both batch halves gathered
// by 8 lanes per (n,k,t) -> ONE fully-used 128B line request per gather
// (half the VMEM requests of the quad-per-half layout).
__global__ __launch_bounds__(256) void fused_main(
    const unsigned short* __restrict__ xth,  // [N][2][32] fp16
    const unsigned short* __restrict__ Wrh,  // [25][64][32] fp16
    const float* __restrict__ bias,          // [64]
    const int* __restrict__ nidx,            // [N][25][3]
    const float* __restrict__ nw,            // [N][25][3]
    float* __restrict__ out,                 // [2][64][N] fp32
    int N)
{
    __shared__ unsigned int idxw[32 * 75];               // [nl][75]: j | half(w)<<16
    __shared__ __align__(16) unsigned char sA[2][4096];  // dbuf: 64 rows (2b x 32n) x 64B
    __shared__ __align__(16) unsigned char sB[2][4096];  // dbuf: 64 o-rows x 64B

    const int tid = threadIdx.x;
    const int n0 = blockIdx.x * 32;

    // ---- stage packed (idx, half(w)): 32 n x 75 words, coalesced ----
#pragma unroll
    for (int it = 0; it < 10; ++it) {
        int e = tid + 256 * it;
        if (e < 2400) {
            int n = n0 + e / 75;
            unsigned int u = 0;
            if (n < N) {
                size_t s = (size_t)n0 * 75 + e;
                int j = nidx[s];
                __half hw = __float2half(nw[s]);
                u = (unsigned int)j |
                    ((unsigned int)*reinterpret_cast<unsigned short*>(&hw) << 16);
            }
            idxw[e] = u;
        }
    }
    __syncthreads();

    const int nl = tid >> 3;                   // n-row 0..31 this thread gathers
    const int p  = tid & 7;                    // 16B slice of the 128B pair-line
    const int grow = (p >> 2) * 32 + nl;       // sA row = b*32 + nl
    const int q = p & 3;                       // c-quad within the 64B half
    const int wr_off = grow * 64 + (SWZ(grow, q) << 4);

    // sB staging: thread t -> o-row tid>>2, c-quad tid&3 (4KB slice)
    const int sbo = (tid >> 2) * 64 + (SWZ((tid >> 2), (tid & 3)) << 4);

    const int l = tid & 63, wv = tid >> 6, c16 = l & 15, g = l >> 4;
    const int arow = 16 * wv + c16;
    const int rd_a = arow * 64 + (SWZ(arow, g) << 4);

    const unsigned short* xg = xth + p * 8;    // + j*64 per gather
    const unsigned int* iprow = &idxw[nl * 75];

    unsigned int ru[3][3];
    uint4 rg[3][3];
    uint4 rB;

    f32x4 acc[4];
#pragma unroll
    for (int ot = 0; ot < 4; ++ot) acc[ot] = (f32x4){0.f, 0.f, 0.f, 0.f};

    // ---- prologue: B(0); idx+gathers for slices 0..2 ----
    rB = *reinterpret_cast<const uint4*>(Wrh + tid * 8);
#pragma unroll
    for (int kk = 0; kk < 3; ++kk)
#pragma unroll
        for (int t = 0; t < 3; ++t) ru[kk][t] = iprow[kk * 3 + t];
#pragma unroll
    for (int kk = 0; kk < 3; ++kk)
#pragma unroll
        for (int t = 0; t < 3; ++t)
            rg[kk][t] = *reinterpret_cast<const uint4*>(xg + (ru[kk][t] & 0xffffu) * 64);

#pragma unroll
    for (int k = 0; k < 25; ++k) {
        const int gb = k % 3, buf = k & 1;

        // consume rB -> sB[buf]; refill B(k+1)
        *reinterpret_cast<uint4*>(&sB[buf][sbo]) = rB;
        if (k + 1 < 25)
            rB = *reinterpret_cast<const uint4*>(Wrh + (k + 1) * 2048 + tid * 8);

        // weighted fp16 sum of slice k's 3 gathered slices -> sA[buf]
        {
            __half2 w0 = hi16(ru[gb][0]), w1 = hi16(ru[gb][1]), w2 = hi16(ru[gb][2]);
            uint4 v0 = rg[gb][0], v1 = rg[gb][1], v2 = rg[gb][2];
            uint4 pk; U2H2 c;
            c.h = __hfma2(u_as_h2(v0.x), w0, __hfma2(u_as_h2(v1.x), w1, __hmul2(u_as_h2(v2.x), w2)));
            pk.x = c.u;
            c.h = __hfma2(u_as_h2(v0.y), w0, __hfma2(u_as_h2(v1.y), w1, __hmul2(u_as_h2(v2.y), w2)));
            pk.y = c.u;
            c.h = __hfma2(u_as_h2(v0.z), w0, __hfma2(u_as_h2(v1.z), w1, __hmul2(u_as_h2(v2.z), w2)));
            pk.z = c.u;
            c.h = __hfma2(u_as_h2(v0.w), w0, __hfma2(u_as_h2(v1.w), w1, __hmul2(u_as_h2(v2.w), w2)));
            pk.w = c.u;
            *reinterpret_cast<uint4*>(&sA[buf][wr_off]) = pk;
        }

        // idx words for slice k+3 (drained by the barrier fence below)
        if (k + 3 < 25) {
#pragma unroll
            for (int t = 0; t < 3; ++t) ru[gb][t] = iprow[(k + 3) * 3 + t];
        }

        // one barrier: sA/sB visible + idx ready; vmem prefetch stays in flight
        LDS_BARRIER();

        // issue gathers for slice k+3 immediately (addresses ready, no wait)
        if (k + 3 < 25) {
#pragma unroll
            for (int t = 0; t < 3; ++t)
                rg[gb][t] = *reinterpret_cast<const uint4*>(xg + (ru[gb][t] & 0xffffu) * 64);
        }

        // MFMA: A rows 16wv.., B shared slice
        {
            half8 af = *reinterpret_cast<const half8*>(&sA[buf][rd_a]);
            __builtin_amdgcn_s_setprio(1);
#pragma unroll
            for (int ot = 0; ot < 4; ++ot) {
                int orow = ot * 16 + c16;
                half8 bf = *reinterpret_cast<const half8*>(
                    &sB[buf][orow * 64 + (SWZ(orow, g) << 4)]);
                acc[ot] = __builtin_amdgcn_mfma_f32_16x16x32_f16(af, bf, acc[ot], 0, 0, 0);
            }
            __builtin_amdgcn_s_setprio(0);
        }
    }

    // ---- epilogue: bias + store (D: o = ot*16+c16, row = 16wv+4g+i) ----
#pragma unroll
    for (int ot = 0; ot < 4; ++ot) {
        int o = ot * 16 + c16;
        float bv = bias[o];
#pragma unroll
        for (int i = 0; i < 4; ++i) {
            int mrow = 16 * wv + 4 * g + i;
            int b = mrow >> 5, nn = n0 + (mrow & 31);
            if (nn < N) out[((size_t)b * 64 + o) * N + nn] = acc[ot][i] + bv;
        }
    }
}

extern "C" void kernel_launch(void* const* d_in, const int* in_sizes, int n_in,
                              void* d_out, int out_size, void* d_ws, size_t ws_size,
                              hipStream_t stream) {
    const float* x    = (const float*)d_in[0];   // (2,32,N)
    const float* nw   = (const float*)d_in[1];   // (N,25,3)
    const float* W    = (const float*)d_in[2];   // (64,800)
    const float* bias = (const float*)d_in[3];   // (64,)
    const int*   nidx = (const int*)d_in[4];     // (N,25,3)
    float* out = (float*)d_out;

    int N = in_sizes[0] / 64;  // B*C = 64

    unsigned short* xth = (unsigned short*)d_ws;      // [N][2][32] fp16
    unsigned short* Wrh = xth + (size_t)N * 64;       // [25][64][32] fp16

    int nT = (N + 63) / 64;
    prep_all<<<nT + 25, 256, 0, stream>>>(x, W, xth, Wrh, N, nT);

    fused_main<<<(N + 31) / 32, 256, 0, stream>>>(xth, Wrh, bias, nidx, nw, out, N);
}